// Round 8
// baseline (113.020 us; speedup 1.0000x reference)
//
#include <hip/hip_runtime.h>
#include <cstdint>
#include <cstddef>

#define B_N 4096
#define V_N 6
#define D_N 256
#define CHUNK 8
#define NCHUNK 80              // sum over rows i=0..31 of ceil((i+1)/8)
#define NGRAM (NCHUNK * V_N)   // 480 blocks, 2/CU at 65.7KB LDS -> co-resident

typedef int i32x4 __attribute__((ext_vector_type(4)));

// i8 encoding: q = round(zn * C), C = sqrt(2)*S -> dot_q = C^2 * sim,
// exp arg = acc * (2/C^2). C=298: element clamp at zn=127/298=0.426
// (max expected |zn| ~ 0.38 over 1.6e9 gaussians), acc max C^2 < 2^31.
#define QC 298.0f
#define INV_C2_X2 (2.0f / (QC * QC))

// Monotonic counters (device globals, never reset; survive timed loops and
// rocprof replays). Each launch adds exactly NGRAM tickets to each:
//   g_bar: phase1->phase2 grid barrier (ticket t waits for (t/480+1)*480)
//   g_fin: finalize election ((t % 480)==479 elects one block per launch)
// NO __threadfence anywhere (R5: device fences = cache-wide wbl2/inv storm,
// +100us). Ordering protocol (R6/R7-proven on 480 floats, extended here to
// the 6.3MB znb payload): agent-scope relaxed (sc1, write-through-to-LLC)
// stores -> s_waitcnt vmcnt(0) -> relaxed ticket. Readers: plain loads are
// safe for znb because (a) launch boundary invalidated all L2s, (b) nobody
// reads znb before the barrier, (c) sc1 stores leave no stale/dirty lines
// in any per-XCD L2 -> first read misses to the coherent point.
__device__ int g_bar = 0;
__device__ int g_fin = 0;

// async global->LDS, 16B per lane. LDS dest is wave-uniform base + lane*16.
__device__ __forceinline__ void async_load16(void* lds, const void* gmem) {
  __builtin_amdgcn_global_load_lds(
      (const __attribute__((address_space(1))) unsigned int*)gmem,
      (__attribute__((address_space(3))) unsigned int*)lds,
      16, 0, 0);
}

// Single dispatch, fence-free:
//   phase 1: norm+quantize+pos, wave-per-sample (3840 waves; the 256 extra
//            samples go to the LAST 32 blocks = smallest gram chunks).
//            znb published via agent-scope u32 stores. pos partial stays
//            in registers/LDS across phase 2 (never touches memory here).
//   ticket barrier on g_bar (monotonic, relaxed, s_sleep spin).
//   phase 2: persistent-chunk i8 gram (R7-verbatim 8-wave structure).
//   publish pos+neg per block -> g_fin election -> last block reduces+out.
__global__ __launch_bounds__(512, 4) void mega_kernel(
    const float* __restrict__ z, signed char* __restrict__ znb,
    float* __restrict__ pos_blk, float* __restrict__ neg_blk,
    float* __restrict__ out) {
  __shared__ signed char As[128][256];     // 32 KB, full-K A panel
  __shared__ signed char Bs[2][128][128];  // 2 x 16 KB, B half-panels
  __shared__ float posr[8];                // phase-1 pos partials (persist)
  __shared__ float red[8];
  __shared__ float pr[8], nr[8];
  __shared__ int lastblk;

  const int bx = blockIdx.x;    // 0..479
  const int tid = threadIdx.x;  // 512
  const int lane = tid & 63;
  const int w = tid >> 6;       // wave 0..7

  // ---------------- phase 1: normalize + quantize + pos ----------------
  float pacc = 0.0f;
  {
    const int wave_global = bx * 8 + w;    // 0..3839
#pragma unroll
    for (int rep = 0; rep < 2; ++rep) {
      // rep 0: samples 0..3839. rep 1: samples 3840..4095 on the last 256
      // waves (blocks 448..479 = smallest phase-2 chunks, LPT-balanced).
      if (rep == 1 && wave_global < 3584) break;
      const int b = (rep == 0) ? wave_global : wave_global + 256;

      const float4* zb4 = (const float4*)(z + (size_t)b * (V_N * D_N));
      float4 x[V_N];
#pragma unroll
      for (int v = 0; v < V_N; ++v) x[v] = zb4[v * 64 + lane];

      float s[21];
      {
        int p = 0;
#pragma unroll
        for (int v = 0; v < V_N; ++v)
#pragma unroll
          for (int u = v; u < V_N; ++u) {
            s[p] = x[v].x * x[u].x + x[v].y * x[u].y +
                   x[v].z * x[u].z + x[v].w * x[u].w;
            ++p;
          }
      }
#pragma unroll
      for (int off = 1; off < 64; off <<= 1)
#pragma unroll
        for (int q = 0; q < 21; ++q)
          s[q] += __shfl_xor(s[q], off);

      const int selfidx[V_N] = {0, 6, 11, 15, 18, 20};
      float inv[V_N];
#pragma unroll
      for (int v = 0; v < V_N; ++v) inv[v] = rsqrtf(s[selfidx[v]]);

#pragma unroll
      for (int v = 0; v < V_N; ++v) {
        const float sc = inv[v] * QC;
        int q0 = (int)rintf(fminf(127.0f, fmaxf(-127.0f, x[v].x * sc)));
        int q1 = (int)rintf(fminf(127.0f, fmaxf(-127.0f, x[v].y * sc)));
        int q2 = (int)rintf(fminf(127.0f, fmaxf(-127.0f, x[v].z * sc)));
        int q3 = (int)rintf(fminf(127.0f, fmaxf(-127.0f, x[v].w * sc)));
        int packed = (q0 & 255) | ((q1 & 255) << 8) | ((q2 & 255) << 16)
                   | ((q3 & 255) << 24);
        // agent-scope (sc1) store: lands at the device coherent point, no
        // dirty line stranded in this XCD's L2 (fence-free handoff).
        __hip_atomic_store(
            (int*)(znb + ((size_t)v * B_N + b) * D_N) + lane, packed,
            __ATOMIC_RELAXED, __HIP_MEMORY_SCOPE_AGENT);
      }

      {
        int p = 0;
#pragma unroll
        for (int v = 0; v < V_N; ++v)
#pragma unroll
          for (int u = v; u < V_N; ++u) {
            if (u > v) pacc += __expf(2.0f * (1.0f - s[p] * inv[v] * inv[u]));
            ++p;
          }
      }
    }
  }
  if (lane == 0) posr[w] = pacc;  // wave-uniform; persists across phase 2

  // ---------------- fence-free grid barrier (monotonic ticket) ----------
  asm volatile("s_waitcnt vmcnt(0)" ::: "memory");  // every thread's stores
  __syncthreads();
  if (tid == 0) {
    int t = __hip_atomic_fetch_add(&g_bar, 1, __ATOMIC_RELAXED,
                                   __HIP_MEMORY_SCOPE_AGENT);
    const int target = (t / NGRAM + 1) * NGRAM;
    while (__hip_atomic_load(&g_bar, __ATOMIC_RELAXED,
                             __HIP_MEMORY_SCOPE_AGENT) < target)
      __builtin_amdgcn_s_sleep(1);
  }
  __syncthreads();  // all znb visible: sc1 writes + clean reader caches

  // ---------------- phase 2: persistent-chunk i8 gram (R7 structure) ----
  const int v = bx / NCHUNK;
  const int cid = bx % NCHUNK;

  // map cid -> (row i, chunk rem), big rows first (LPT)
  int i = 31, rem = cid;
  for (int r = 31; r >= 0; --r) {
    const int nc = (r + 8) >> 3;           // ceil((r+1)/8)
    if (rem < nc) { i = r; break; }
    rem -= nc;
  }
  const int j0 = rem * CHUNK;
  const int jend = min(j0 + CHUNK, i + 1);
  const int nsteps = 2 * (jend - j0);

  const signed char* Zv = znb + (size_t)v * B_N * D_N;
  const signed char* Ag = Zv + (size_t)(i * 128) * D_N;

  const int wr = w >> 2;        // wave row 0..1 (64-row strip of C)
  const int wc = w & 3;         // wave col 0..3 (32-col strip of C)
  const int kc = lane >> 4;                // operand 16B-chunk index (0..3)
  const int mrow = wr * 64 + (lane & 15);  // A fragment base row
  const int ncol = wc * 32 + (lane & 15);  // B fragment base row (= C col)

  signed char* AsF = &As[0][0];

  // prologue: issue A (4 load-instrs/thread) + B steps 0,1 (2 each)
#pragma unroll
  for (int q = 0; q < 4; ++q) {
    const int sA = tid + 512 * q;          // 0..2047
    const int row = sA >> 4;               // 0..127
    const int gc = (sA & 15) ^ (row & 15); // 256B-row swizzle on global src
    async_load16(AsF + sA * 16, Ag + (size_t)row * D_N + gc * 16);
  }
#pragma unroll
  for (int st = 0; st < 2; ++st) {
    if (st < nsteps) {
      const int jn = j0 + (st >> 1), hn = st & 1;
      const signed char* Bg = Zv + (size_t)(jn * 128) * D_N + hn * 128;
      signed char* BsF = &Bs[st & 1][0][0];
#pragma unroll
      for (int q = 0; q < 2; ++q) {
        const int s = tid + 512 * q;       // 0..1023
        const int row = s >> 3;            // 0..127
        const int gc = (s & 7) ^ (row & 7);
        async_load16(BsF + s * 16, Bg + (size_t)row * D_N + gc * 16);
      }
    }
  }
  asm volatile("s_waitcnt vmcnt(2)" ::: "memory");
  __builtin_amdgcn_sched_barrier(0);
  __builtin_amdgcn_s_barrier();

  float wsum = 0.0f;
  int s = 0;
  for (int jt = j0; jt < jend; ++jt) {
    i32x4 c[4][2];
#pragma unroll
    for (int a = 0; a < 4; ++a)
#pragma unroll
      for (int b2 = 0; b2 < 2; ++b2) c[a][b2] = (i32x4){0, 0, 0, 0};

#pragma unroll
    for (int h = 0; h < 2; ++h, ++s) {
      const signed char* BsF = &Bs[s & 1][0][0];
      __builtin_amdgcn_s_setprio(1);
#pragma unroll
      for (int kk = 0; kk < 2; ++kk) {
        const int cb8 = kk * 4 + kc;           // B chunk 0..7 (128B rows)
        const int ca16 = h * 8 + kk * 4 + kc;  // A chunk 0..15 (256B rows)
        i32x4 af[4], bfr[2];
#pragma unroll
        for (int f = 0; f < 4; ++f) {
          const int ra = mrow + 16 * f;
          af[f] = *(const i32x4*)(AsF + ra * 256 + ((ca16 ^ (ra & 15)) * 16));
        }
#pragma unroll
        for (int f = 0; f < 2; ++f) {
          const int rb = ncol + 16 * f;
          bfr[f] = *(const i32x4*)(BsF + rb * 128 + ((cb8 ^ (rb & 7)) * 16));
        }
#pragma unroll
        for (int fm = 0; fm < 4; ++fm)
#pragma unroll
          for (int fn = 0; fn < 2; ++fn)
            c[fm][fn] = __builtin_amdgcn_mfma_i32_16x16x64_i8(
                af[fm], bfr[fn], c[fm][fn], 0, 0, 0);
      }
      __builtin_amdgcn_s_setprio(0);
      __builtin_amdgcn_s_barrier();  // Bs[s&1] reads done before overwrite
      const int sn = s + 2;
      if (sn < nsteps) {
        const int jn = j0 + (sn >> 1), hn = sn & 1;
        const signed char* Bg = Zv + (size_t)(jn * 128) * D_N + hn * 128;
        signed char* BsN = &Bs[s & 1][0][0];
#pragma unroll
        for (int q = 0; q < 2; ++q) {
          const int sg = tid + 512 * q;
          const int row = sg >> 3;
          const int gc = (sg & 7) ^ (row & 7);
          async_load16(BsN + sg * 16, Bg + (size_t)row * D_N + gc * 16);
        }
      }
      // tile epilogue (pure VALU) overlaps S(s+1) flight; diag test hoisted
      if (h == 1) {
        float tsum = 0.0f;
        if (i != jt) {
#pragma unroll
          for (int fm = 0; fm < 4; ++fm)
#pragma unroll
            for (int fn = 0; fn < 2; ++fn)
#pragma unroll
              for (int r = 0; r < 4; ++r)
                tsum += __expf((float)c[fm][fn][r] * INV_C2_X2);
          wsum += 2.0f * tsum;             // symmetric twin tile
        } else {
          const int rb0 = wr * 64 + (lane >> 4) * 4;  // local row in tile
          const int cb0 = wc * 32 + (lane & 15);      // local col in tile
#pragma unroll
          for (int fm = 0; fm < 4; ++fm)
#pragma unroll
            for (int fn = 0; fn < 2; ++fn) {
              const int gcol = cb0 + fn * 16;
#pragma unroll
              for (int r = 0; r < 4; ++r) {
                const int grow = rb0 + fm * 16 + r;
                float e = __expf((float)c[fm][fn][r] * INV_C2_X2);
                tsum += (grow == gcol) ? 0.0f : e;
              }
            }
          wsum += tsum;
        }
      }
      if (sn < nsteps) {
        asm volatile("s_waitcnt vmcnt(2)" ::: "memory");
      } else {
        asm volatile("s_waitcnt vmcnt(0)" ::: "memory");
      }
      __builtin_amdgcn_sched_barrier(0);
      __builtin_amdgcn_s_barrier();
    }
  }

  // per-block reduction, fence-free publish (pos + neg) + election
#pragma unroll
  for (int off = 32; off > 0; off >>= 1) wsum += __shfl_down(wsum, off);
  if (lane == 0) red[w] = wsum;
  __syncthreads();
  if (tid == 0) {
    float bneg = 0.0f, bpos = 0.0f;
#pragma unroll
    for (int k = 0; k < 8; ++k) { bneg += red[k]; bpos += posr[k]; }
    __hip_atomic_store(&neg_blk[bx], bneg, __ATOMIC_RELAXED,
                       __HIP_MEMORY_SCOPE_AGENT);
    __hip_atomic_store(&pos_blk[bx], bpos, __ATOMIC_RELAXED,
                       __HIP_MEMORY_SCOPE_AGENT);
    asm volatile("s_waitcnt vmcnt(0)" ::: "memory");
    int t2 = __hip_atomic_fetch_add(&g_fin, 1, __ATOMIC_RELAXED,
                                    __HIP_MEMORY_SCOPE_AGENT);
    lastblk = ((t2 % NGRAM) == NGRAM - 1) ? 1 : 0;
  }
  __syncthreads();

  if (lastblk) {
    // partials written this-dispatch on other XCDs -> agent-scope loads
    // (R4/R6/R7-verified read path, absmax 0.0).
    float p = 0.0f, n = 0.0f;
    for (int idx = tid; idx < NGRAM; idx += 512) {
      p += __hip_atomic_load(&pos_blk[idx], __ATOMIC_RELAXED,
                             __HIP_MEMORY_SCOPE_AGENT);
      n += __hip_atomic_load(&neg_blk[idx], __ATOMIC_RELAXED,
                             __HIP_MEMORY_SCOPE_AGENT);
    }
#pragma unroll
    for (int off = 32; off > 0; off >>= 1) {
      p += __shfl_down(p, off);
      n += __shfl_down(n, off);
    }
    if (lane == 0) { pr[w] = p; nr[w] = n; }
    __syncthreads();
    if (tid == 0) {
      float P = 0.0f, N = 0.0f;
#pragma unroll
      for (int k = 0; k < 8; ++k) { P += pr[k]; N += nr[k]; }
      // sum(pos) = (6*B + 2P)/36 = B/6 + P/18 ; sum(neg) = N/(B-1)
      out[0] = (1.0f / 32.0f) * ((float)B_N / 6.0f + P / 18.0f) +
               0.0039f * (N / (float)(B_N - 1));
    }
  }
}

extern "C" void kernel_launch(void* const* d_in, const int* in_sizes, int n_in,
                              void* d_out, int out_size, void* d_ws, size_t ws_size,
                              hipStream_t stream) {
  const float* z = (const float*)d_in[0];
  float* out = (float*)d_out;
  // ws: [0, 2KB) pos partials (480 f32) | 8KB: neg partials (480 f32) |
  //     32KB: i8 Zn [V][B][D] (6.3 MB). All fully overwritten every launch.
  //     Barrier/election counters are __device__ globals (monotonic).
  float* pos_blk = (float*)d_ws;
  float* neg_blk = (float*)((char*)d_ws + 8192);
  signed char* znb = (signed char*)((char*)d_ws + 32768);

  mega_kernel<<<NGRAM, 512, 0, stream>>>(z, znb, pos_blk, neg_blk, out);
}

// Round 9
// 98.401 us; speedup vs baseline: 1.1486x; 1.1486x over previous
//
#include <hip/hip_runtime.h>
#include <cstdint>
#include <cstddef>

#define B_N 4096
#define V_N 6
#define D_N 256
#define CHUNK 8
#define NCHUNK 80              // sum over rows i=0..31 of ceil((i+1)/8)
#define NGRAM (NCHUNK * V_N)   // 480 gram blocks
#define NPOSB 1024             // norm_pos blocks (block partials)

typedef int i32x4 __attribute__((ext_vector_type(4)));

// i8 encoding: q = round(zn * C), C = sqrt(2)*S -> dot_q = C^2 * sim,
// exp arg = acc * (2/C^2). C=298: element clamp at zn=127/298=0.426
// (max expected |zn| ~ 0.38 over 1.6e9 gaussians), acc max C^2 < 2^31.
#define QC 298.0f
#define INV_C2_X2 (2.0f / (QC * QC))

// Monotonic election counter (device global, never reset): each gram launch
// adds exactly NGRAM tickets -> (t % NGRAM)==NGRAM-1 elects one block per
// launch; survives timed loops and rocprof replays. NO __threadfence
// anywhere (R5: device fences = cache-wide wbl2/inv storm). Ordering:
// agent-scope relaxed store -> s_waitcnt vmcnt(0) -> relaxed ticket.
__device__ int g_fin = 0;

// async global->LDS, 16B per lane. LDS dest is wave-uniform base + lane*16.
__device__ __forceinline__ void async_load16(void* lds, const void* gmem) {
  __builtin_amdgcn_global_load_lds(
      (const __attribute__((address_space(1))) unsigned int*)gmem,
      (__attribute__((address_space(3))) unsigned int*)lds,
      16, 0, 0);
}

// Kernel A (R6/R7-verbatim): wave-per-sample, register-resident.
// 21 simultaneous 6-step shfl_xor butterflies; per-block pos partial.
// Runs at high occupancy as its own dispatch (R8 lesson: fusing it into
// the LDS-heavy gram kernel costs 3-4x on this phase).
__global__ __launch_bounds__(256) void norm_pos_kernel(
    const float* __restrict__ z, signed char* __restrict__ znb,
    float* __restrict__ pos_blk) {
  const int lane = threadIdx.x & 63;
  const int w = threadIdx.x >> 6;          // wave 0..3
  const int b = blockIdx.x * 4 + w;        // sample
  __shared__ float red[4];

  const float4* zb4 = (const float4*)(z + (size_t)b * (V_N * D_N));
  float4 x[V_N];
#pragma unroll
  for (int v = 0; v < V_N; ++v) x[v] = zb4[v * 64 + lane];

  float s[21];
  {
    int p = 0;
#pragma unroll
    for (int v = 0; v < V_N; ++v)
#pragma unroll
      for (int u = v; u < V_N; ++u) {
        s[p] = x[v].x * x[u].x + x[v].y * x[u].y +
               x[v].z * x[u].z + x[v].w * x[u].w;
        ++p;
      }
  }
#pragma unroll
  for (int off = 1; off < 64; off <<= 1)
#pragma unroll
    for (int q = 0; q < 21; ++q)
      s[q] += __shfl_xor(s[q], off);

  const int selfidx[V_N] = {0, 6, 11, 15, 18, 20};
  float inv[V_N];
#pragma unroll
  for (int v = 0; v < V_N; ++v) inv[v] = rsqrtf(s[selfidx[v]]);

#pragma unroll
  for (int v = 0; v < V_N; ++v) {
    const float sc = inv[v] * QC;
    int q0 = (int)rintf(fminf(127.0f, fmaxf(-127.0f, x[v].x * sc)));
    int q1 = (int)rintf(fminf(127.0f, fmaxf(-127.0f, x[v].y * sc)));
    int q2 = (int)rintf(fminf(127.0f, fmaxf(-127.0f, x[v].z * sc)));
    int q3 = (int)rintf(fminf(127.0f, fmaxf(-127.0f, x[v].w * sc)));
    int packed = (q0 & 255) | ((q1 & 255) << 8) | ((q2 & 255) << 16)
               | ((q3 & 255) << 24);
    ((int*)(znb + ((size_t)v * B_N + b) * D_N))[lane] = packed;
  }

  float psum = 0.0f;
  {
    int p = 0;
#pragma unroll
    for (int v = 0; v < V_N; ++v)
#pragma unroll
      for (int u = v; u < V_N; ++u) {
        if (u > v) psum += __expf(2.0f * (1.0f - s[p] * inv[v] * inv[u]));
        ++p;
      }
  }
  if (lane == 0) red[w] = psum;
  __syncthreads();
  if (threadIdx.x == 0)
    pos_blk[blockIdx.x] = red[0] + red[1] + red[2] + red[3];
}

// Kernel B: persistent-chunk i8 gram, now 1024 threads / 16 waves per block
// over the same 128x128 tile (wave grid 4x4, per-wave 32x32 sub-tile,
// c[2][2] acc = 16 VGPR). launch_bounds(1024,8) caps VGPR at 64 ->
// 8 waves/SIMD -> 2 blocks/CU = 32 waves/CU (hardware max), doubling R7's
// latency hiding for the per-step barrier+load-return holes. Per-thread
// staging drops to 2(A)+1(B) loads; per-thread epilogue halves to 16 exp.
// Fence-free last-block finalize (R6/R7-verified).
__global__ __launch_bounds__(1024, 8) void gram_kernel(
    const signed char* __restrict__ znb, const float* __restrict__ pos_blk,
    float* __restrict__ neg_blk, float* __restrict__ out) {
  const int v = blockIdx.y;
  const int bid = blockIdx.y * NCHUNK + blockIdx.x;

  // map blockIdx.x -> (row i, chunk rem), big rows first (LPT dispatch)
  int i = 31, rem = blockIdx.x;
  for (int r = 31; r >= 0; --r) {
    const int nc = (r + 8) >> 3;           // ceil((r+1)/8)
    if (rem < nc) { i = r; break; }
    rem -= nc;
  }
  const int j0 = rem * CHUNK;
  const int jend = min(j0 + CHUNK, i + 1);
  const int nsteps = 2 * (jend - j0);

  const signed char* Zv = znb + (size_t)v * B_N * D_N;
  const signed char* Ag = Zv + (size_t)(i * 128) * D_N;

  __shared__ signed char As[128][256];     // 32 KB, full-K A panel
  __shared__ signed char Bs[2][128][128];  // 2 x 16 KB, B half-panels
  __shared__ float red[16];
  __shared__ float pr[16], nr[16];
  __shared__ int lastblk;

  const int tid = threadIdx.x;  // 1024
  const int lane = tid & 63;
  const int w = tid >> 6;       // wave 0..15
  const int wr = w >> 2;        // wave row 0..3 (32-row strip of C)
  const int wc = w & 3;         // wave col 0..3 (32-col strip of C)
  const int kc = lane >> 4;                // operand 16B-chunk index (0..3)
  const int mrow = wr * 32 + (lane & 15);  // A fragment base row
  const int ncol = wc * 32 + (lane & 15);  // B fragment base row (= C col)

  signed char* AsF = &As[0][0];

  // prologue: issue A (2 load-instrs/thread) + B steps 0,1 (1 each)
#pragma unroll
  for (int q = 0; q < 2; ++q) {
    const int sA = tid + 1024 * q;         // 0..2047
    const int row = sA >> 4;               // 0..127
    const int gc = (sA & 15) ^ (row & 15); // 256B-row swizzle on global src
    async_load16(AsF + sA * 16, Ag + (size_t)row * D_N + gc * 16);
  }
#pragma unroll
  for (int st = 0; st < 2; ++st) {
    if (st < nsteps) {
      const int jn = j0 + (st >> 1), hn = st & 1;
      const signed char* Bg = Zv + (size_t)(jn * 128) * D_N + hn * 128;
      signed char* BsF = &Bs[st & 1][0][0];
      const int s = tid;                   // 0..1023
      const int row = s >> 3;              // 0..127
      const int gc = (s & 7) ^ (row & 7);
      async_load16(BsF + s * 16, Bg + (size_t)row * D_N + gc * 16);
    }
  }
  // A(2) + S0(1) landed; S1(1) may still be in flight
  asm volatile("s_waitcnt vmcnt(1)" ::: "memory");
  __builtin_amdgcn_sched_barrier(0);
  __builtin_amdgcn_s_barrier();

  float wsum = 0.0f;
  int s = 0;
  for (int jt = j0; jt < jend; ++jt) {
    i32x4 c[2][2];
#pragma unroll
    for (int a = 0; a < 2; ++a)
#pragma unroll
      for (int b2 = 0; b2 < 2; ++b2) c[a][b2] = (i32x4){0, 0, 0, 0};

#pragma unroll
    for (int h = 0; h < 2; ++h, ++s) {
      const signed char* BsF = &Bs[s & 1][0][0];
      __builtin_amdgcn_s_setprio(1);
#pragma unroll
      for (int kk = 0; kk < 2; ++kk) {
        const int cb8 = kk * 4 + kc;           // B chunk 0..7 (128B rows)
        const int ca16 = h * 8 + kk * 4 + kc;  // A chunk 0..15 (256B rows)
        i32x4 af[2], bfr[2];
#pragma unroll
        for (int f = 0; f < 2; ++f) {
          const int ra = mrow + 16 * f;
          af[f] = *(const i32x4*)(AsF + ra * 256 + ((ca16 ^ (ra & 15)) * 16));
        }
#pragma unroll
        for (int f = 0; f < 2; ++f) {
          const int rb = ncol + 16 * f;
          bfr[f] = *(const i32x4*)(BsF + rb * 128 + ((cb8 ^ (rb & 7)) * 16));
        }
#pragma unroll
        for (int fm = 0; fm < 2; ++fm)
#pragma unroll
          for (int fn = 0; fn < 2; ++fn)
            c[fm][fn] = __builtin_amdgcn_mfma_i32_16x16x64_i8(
                af[fm], bfr[fn], c[fm][fn], 0, 0, 0);
      }
      __builtin_amdgcn_s_setprio(0);
      __builtin_amdgcn_s_barrier();  // Bs[s&1] reads done before overwrite
      const int sn = s + 2;
      if (sn < nsteps) {
        const int jn = j0 + (sn >> 1), hn = sn & 1;
        const signed char* Bg = Zv + (size_t)(jn * 128) * D_N + hn * 128;
        signed char* BsN = &Bs[s & 1][0][0];
        const int sg = tid;
        const int row = sg >> 3;
        const int gc = (sg & 7) ^ (row & 7);
        async_load16(BsN + sg * 16, Bg + (size_t)row * D_N + gc * 16);
      }
      // tile epilogue (pure VALU) overlaps S(s+1) flight; diag test hoisted
      if (h == 1) {
        float tsum = 0.0f;
        if (i != jt) {
#pragma unroll
          for (int fm = 0; fm < 2; ++fm)
#pragma unroll
            for (int fn = 0; fn < 2; ++fn)
#pragma unroll
              for (int r = 0; r < 4; ++r)
                tsum += __expf((float)c[fm][fn][r] * INV_C2_X2);
          wsum += 2.0f * tsum;             // symmetric twin tile
        } else {
          const int rb0 = wr * 32 + (lane >> 4) * 4;  // local row in tile
          const int cb0 = wc * 32 + (lane & 15);      // local col in tile
#pragma unroll
          for (int fm = 0; fm < 2; ++fm)
#pragma unroll
            for (int fn = 0; fn < 2; ++fn) {
              const int gcol = cb0 + fn * 16;
#pragma unroll
              for (int r = 0; r < 4; ++r) {
                const int grow = rb0 + fm * 16 + r;
                float e = __expf((float)c[fm][fn][r] * INV_C2_X2);
                tsum += (grow == gcol) ? 0.0f : e;
              }
            }
          wsum += tsum;
        }
      }
      if (sn < nsteps) {
        asm volatile("s_waitcnt vmcnt(1)" ::: "memory");
      } else {
        asm volatile("s_waitcnt vmcnt(0)" ::: "memory");
      }
      __builtin_amdgcn_sched_barrier(0);
      __builtin_amdgcn_s_barrier();
    }
  }

  // per-block reduction, fence-free publish + monotonic election
#pragma unroll
  for (int off = 32; off > 0; off >>= 1) wsum += __shfl_down(wsum, off);
  if (lane == 0) red[w] = wsum;
  __syncthreads();
  if (tid == 0) {
    float bsum = 0.0f;
#pragma unroll
    for (int k = 0; k < 16; ++k) bsum += red[k];
    // agent-scope relaxed store -> visible at the device coherent point...
    __hip_atomic_store(&neg_blk[bid], bsum, __ATOMIC_RELAXED,
                       __HIP_MEMORY_SCOPE_AGENT);
    // ...and COMPLETE before the ticket increments (no wbl2/inv needed)
    asm volatile("s_waitcnt vmcnt(0)" ::: "memory");
    int t2 = __hip_atomic_fetch_add(&g_fin, 1, __ATOMIC_RELAXED,
                                    __HIP_MEMORY_SCOPE_AGENT);
    lastblk = ((t2 % NGRAM) == NGRAM - 1) ? 1 : 0;
  }
  __syncthreads();

  if (lastblk) {
    // pos_blk: previous dispatch -> plain loads coherent. neg_blk: written
    // this-dispatch on other XCDs -> agent-scope loads (R4/R6/R7-verified).
    float p = 0.0f, n = 0.0f;
    for (int idx = tid; idx < NPOSB; idx += 1024) p += pos_blk[idx];
    for (int idx = tid; idx < NGRAM; idx += 1024)
      n += __hip_atomic_load(&neg_blk[idx], __ATOMIC_RELAXED,
                             __HIP_MEMORY_SCOPE_AGENT);
#pragma unroll
    for (int off = 32; off > 0; off >>= 1) {
      p += __shfl_down(p, off);
      n += __shfl_down(n, off);
    }
    if (lane == 0) { pr[w] = p; nr[w] = n; }
    __syncthreads();
    if (tid == 0) {
      float P = 0.0f, N = 0.0f;
#pragma unroll
      for (int k = 0; k < 16; ++k) { P += pr[k]; N += nr[k]; }
      // sum(pos) = (6*B + 2P)/36 = B/6 + P/18 ; sum(neg) = N/(B-1)
      out[0] = (1.0f / 32.0f) * ((float)B_N / 6.0f + P / 18.0f) +
               0.0039f * (N / (float)(B_N - 1));
    }
  }
}

extern "C" void kernel_launch(void* const* d_in, const int* in_sizes, int n_in,
                              void* d_out, int out_size, void* d_ws, size_t ws_size,
                              hipStream_t stream) {
  const float* z = (const float*)d_in[0];
  float* out = (float*)d_out;
  // ws: [0, 4KB) pos partials (1024 f32) | 8KB: neg partials (480 f32) |
  //     32KB: i8 Zn [V][B][D] (6.3 MB). All fully overwritten every launch.
  //     Election counter is a __device__ global (monotonic, no init).
  float* pos_blk = (float*)d_ws;
  float* neg_blk = (float*)((char*)d_ws + 8192);
  signed char* znb = (signed char*)((char*)d_ws + 32768);

  norm_pos_kernel<<<NPOSB, 256, 0, stream>>>(z, znb, pos_blk);
  dim3 grid(NCHUNK, V_N, 1);
  gram_kernel<<<grid, 1024, 0, stream>>>(znb, pos_blk, neg_blk, out);
}